// Round 1
// baseline (7341.238 us; speedup 1.0000x reference)
//
#include <hip/hip_runtime.h>

// MLPProjectionFilter: 15-iter ADMM projection, B=2048 samples, fp32.
// Identities used: s=relu(b-Ax), res=relu(Ax-b), b-s=min(b,Ax)=u.
// Per iter: K1 (per-sample: lam update, norms, rhs, Qinv^T matvec, c write)
//           K2 (big: Avx=A*c forward; A^T res and A^T u transpose; sq partials)
// dl/G and sq are written as per-chunk partials (no global atomics), summed in K1/K3.

#define BATCH 2048
#define NVAR 192
#define NCON 1200
#define NEQ 30
#define NT 222          // NVAR + NEQ
#define MAXITER 15
#define MTILE 16        // samples per K2 workgroup
#define NTILE (BATCH / MTILE)   // 128
#define CHUNK 300       // NCON rows per K2 chunk
#define NCHUNK 4

// workspace layout (float offsets)
#define O_LAM 0u
#define SZ_LAM (BATCH*576)
#define O_C   (O_LAM + SZ_LAM)
#define SZ_C  (BATCH*NVAR)
#define O_U   (O_C + SZ_C)
#define SZ_U  (BATCH*3*NCON)
#define O_DLG (O_U + SZ_U)                 // [NCHUNK][BATCH][768]: dl_v,dl_a,dl_p,G
#define SZ_DLG (NCHUNK*BATCH*768)
#define O_SQ  (O_DLG + SZ_DLG)             // [NCHUNK][BATCH][8]: res_v,a,p, sd_v,a,p
#define SZ_SQ (NCHUNK*BATCH*8)
#define O_TOT (O_SQ + SZ_SQ)               // [BATCH][2]: fp_tot, rp_tot
#define SZ_TOT (BATCH*2)
#define O_QT  (O_TOT + SZ_TOT)             // Qinv transposed: [NT][NVAR]
#define SZ_QT (NT*NVAR)
#define WS_FLOATS (O_QT + SZ_QT)           // ~15.35M floats = ~61.4 MB

__global__ __launch_bounds__(256) void kz(float* __restrict__ p, int n) {
  int idx = blockIdx.x * 256 + threadIdx.x;
  if (idx < n) p[idx] = 0.f;
}

__global__ __launch_bounds__(256) void ki(const float* __restrict__ lamda,
                                          const float* __restrict__ c0,
                                          const float* __restrict__ Qinv,
                                          float* __restrict__ lamW,
                                          float* __restrict__ cW,
                                          float* __restrict__ QT) {
  int idx = blockIdx.x * 256 + threadIdx.x;
  if (idx < BATCH*576) { lamW[idx] = lamda[idx]; return; }
  idx -= BATCH*576;
  if (idx < BATCH*NVAR) { cW[idx] = c0[idx]; return; }
  idx -= BATCH*NVAR;
  if (idx < NT*NVAR) {
    int j = idx / NVAR, i = idx - j*NVAR;
    QT[idx] = Qinv[(size_t)i*NT + j];     // QT[j][i] = Qinv[i][j]
  }
}

// K2: the A-stream kernel. grid = NCHUNK*NTILE, block=256.
__global__ __launch_bounds__(256) void k2(const float* __restrict__ cS,
    const float* __restrict__ Av, const float* __restrict__ Aa, const float* __restrict__ Ap,
    float* __restrict__ uW, float* __restrict__ dlG, float* __restrict__ sqP, int first)
{
  __shared__ float avxL[MTILE][CHUNK + 4];    // [m][rloc], stride 304 (conflict-free)
  __shared__ float sqAcc[3][2][MTILE];        // [mat][res/sd][m]
  const int tid  = threadIdx.x;
  const int tile = blockIdx.x & (NTILE - 1);
  const int chunk = blockIdx.x >> 7;
  const int tile0 = tile * MTILE;
  const int r0 = chunk * CHUNK;
  const int lane = tid & 63;
  const int wave = tid >> 6;

  if (tid < 96) ((float*)sqAcc)[tid] = 0.f;

  float Greg[3][4];                           // G = sum_mat A^T u, cols lane+64j, m=wave*4+mi
  #pragma unroll
  for (int j = 0; j < 3; ++j)
    #pragma unroll
    for (int mi = 0; mi < 4; ++mi) Greg[j][mi] = 0.f;

  #pragma unroll
  for (int mat = 0; mat < 3; ++mat) {
    const float b = (mat == 0) ? 0.8f : ((mat == 1) ? 1.8f : 3.14159265358979f);
    const float* __restrict__ A = (mat == 0) ? Av : ((mat == 1) ? Aa : Ap);

    float ressq[MTILE], sdsq[MTILE];
    #pragma unroll
    for (int m = 0; m < MTILE; ++m) { ressq[m] = 0.f; sdsq[m] = 0.f; }

    __syncthreads();   // avxL free (prev transpose done / sqAcc zeroed)

    // ---- forward: Avx[r][m] = A[r][:] . c[m][:], thread = row ----
    #pragma unroll 1
    for (int pass = 0; pass < 2; ++pass) {
      const int rloc = pass * 256 + tid;
      if (rloc < CHUNK) {
        const int rg = r0 + rloc;
        float acc[MTILE];
        #pragma unroll
        for (int m = 0; m < MTILE; ++m) acc[m] = 0.f;
        const float4* __restrict__ Arow = (const float4*)(A + (size_t)rg * NVAR);
        #pragma unroll 2
        for (int k4 = 0; k4 < NVAR/4; ++k4) {
          const float4 a = Arow[k4];
          #pragma unroll
          for (int m = 0; m < MTILE; ++m) {
            // uniform address -> scalar load + broadcast
            const float4 c = ((const float4*)(cS + (size_t)(tile0 + m) * NVAR))[k4];
            acc[m] = fmaf(a.x, c.x, fmaf(a.y, c.y, fmaf(a.z, c.z, fmaf(a.w, c.w, acc[m]))));
          }
        }
        #pragma unroll
        for (int m = 0; m < MTILE; ++m) {
          const float v = acc[m];
          avxL[m][rloc] = v;
          const float u = fminf(v, b);
          const size_t ui = (size_t)(tile0 + m) * (3*NCON) + (size_t)mat * NCON + rg;
          if (!first) {
            const float up = uW[ui];
            const float sd = u - up;            // s_t - s_{t-1} = u_{t-1} - u_t (sign-free in square)
            sdsq[m] += sd * sd;
            const float rs = fmaxf(v - b, 0.f); // res = relu(Avx - b)
            ressq[m] += rs * rs;
          }
          uW[ui] = u;
        }
      }
    }

    if (!first) {   // reduce per-m sq partials across the wave, then 4 LDS adds
      #pragma unroll
      for (int m = 0; m < MTILE; ++m) {
        float v1 = ressq[m], v2 = sdsq[m];
        #pragma unroll
        for (int off = 32; off >= 1; off >>= 1) {
          v1 += __shfl_xor(v1, off);
          v2 += __shfl_xor(v2, off);
        }
        if (lane == 0) {
          atomicAdd(&sqAcc[mat][0][m], v1);
          atomicAdd(&sqAcc[mat][1][m], v2);
        }
      }
    }

    __syncthreads();   // avxL ready

    // ---- transpose: dl[m][col] += A[r][col]*res, G += A[r][col]*u ----
    float dl[3][4];
    #pragma unroll
    for (int j = 0; j < 3; ++j)
      #pragma unroll
      for (int mi = 0; mi < 4; ++mi) dl[j][mi] = 0.f;

    const float* __restrict__ Abase = A + (size_t)r0 * NVAR + lane;
    #pragma unroll 1
    for (int r = 0; r < CHUNK; ++r) {
      const float am0 = Abase[(size_t)r * NVAR];
      const float am1 = Abase[(size_t)r * NVAR + 64];
      const float am2 = Abase[(size_t)r * NVAR + 128];
      #pragma unroll
      for (int mi = 0; mi < 4; ++mi) {
        const float v = avxL[wave*4 + mi][r];   // LDS broadcast within wave
        const float u = fminf(v, b);
        Greg[0][mi] = fmaf(am0, u, Greg[0][mi]);
        Greg[1][mi] = fmaf(am1, u, Greg[1][mi]);
        Greg[2][mi] = fmaf(am2, u, Greg[2][mi]);
        if (!first) {
          const float rs = fmaxf(v - b, 0.f);
          dl[0][mi] = fmaf(am0, rs, dl[0][mi]);
          dl[1][mi] = fmaf(am1, rs, dl[1][mi]);
          dl[2][mi] = fmaf(am2, rs, dl[2][mi]);
        }
      }
    }
    if (!first) {
      #pragma unroll
      for (int mi = 0; mi < 4; ++mi)
        #pragma unroll
        for (int j = 0; j < 3; ++j)
          dlG[((size_t)chunk*BATCH + tile0 + wave*4 + mi)*768 + mat*NVAR + lane + 64*j] = dl[j][mi];
    }
  }

  // flush G (also in prime pass)
  #pragma unroll
  for (int mi = 0; mi < 4; ++mi)
    #pragma unroll
    for (int j = 0; j < 3; ++j)
      dlG[((size_t)chunk*BATCH + tile0 + wave*4 + mi)*768 + 576 + lane + 64*j] = Greg[j][mi];

  __syncthreads();
  if (!first && tid < 96) {
    const int s = tid & 15, slot = tid >> 4;       // slot 0..5
    const int mat  = (slot < 3) ? slot : slot - 3;
    const int kind = (slot < 3) ? 0 : 1;
    sqP[((size_t)chunk*BATCH + tile0 + s)*8 + slot] = sqAcc[mat][kind][s];
  }
}

// K1: per-sample small solve. grid = BATCH/8, block=256, 8 samples/WG.
__global__ __launch_bounds__(256) void k1(const float* __restrict__ cin,
    const float* __restrict__ beq, const float* __restrict__ QT,
    float* __restrict__ lamW, float* __restrict__ cW,
    const float* __restrict__ dlG, const float* __restrict__ sqP,
    float* __restrict__ tot)
{
  __shared__ float dlL[8][768];
  __shared__ float lamL[8][576];
  __shared__ float rhsL[8][NT];
  __shared__ float sqL[8][4];
  const int tid = threadIdx.x;
  const int sb = blockIdx.x * 8;
  if (tid < 32) ((float*)sqL)[tid] = 0.f;
  // sum dl/G chunk partials
  for (int idx = tid; idx < 8*768; idx += 256) {
    const int s = idx / 768, e = idx - s*768;
    const size_t base = (size_t)(sb + s)*768 + e;
    dlL[s][e] = dlG[base] + dlG[(size_t)BATCH*768 + base]
              + dlG[2*(size_t)BATCH*768 + base] + dlG[3*(size_t)BATCH*768 + base];
  }
  __syncthreads();
  // lam update + ||dl|| partials
  for (int idx = tid; idx < 8*576; idx += 256) {
    const int s = idx / 576, e = idx - s*576;
    const size_t g = (size_t)(sb + s)*576 + e;
    const float d = dlL[s][e];
    const float ln = lamW[g] - d;
    lamW[g] = ln;
    lamL[s][e] = ln;
    atomicAdd(&sqL[s][e / NVAR], d * d);
  }
  __syncthreads();
  // rhs = [lam_v+lam_a+lam_p + c_in + G ; b_eq]
  for (int idx = tid; idx < 8*NT; idx += 256) {
    const int s = idx / NT, j = idx - s*NT;
    float v;
    if (j < NVAR)
      v = lamL[s][j] + lamL[s][NVAR + j] + lamL[s][2*NVAR + j]
        + cin[(size_t)(sb + s)*NVAR + j] + dlL[s][576 + j];
    else
      v = beq[(size_t)(sb + s)*NEQ + (j - NVAR)];
    rhsL[s][j] = v;
  }
  __syncthreads();
  // primal[i] = sum_j QT[j][i] * rhs[j]
  if (tid < NVAR) {
    float acc[8];
    #pragma unroll
    for (int s = 0; s < 8; ++s) acc[s] = 0.f;
    #pragma unroll 2
    for (int j = 0; j < NT; ++j) {
      const float q = QT[(size_t)j*NVAR + tid];
      #pragma unroll
      for (int s = 0; s < 8; ++s) acc[s] = fmaf(q, rhsL[s][j], acc[s]);
    }
    #pragma unroll
    for (int s = 0; s < 8; ++s) {
      const size_t g = (size_t)(sb + s)*NVAR + tid;
      const float co = cW[g];
      const float d = acc[s] - co;
      atomicAdd(&sqL[s][3], d * d);
      cW[g] = acc[s];
    }
  }
  __syncthreads();
  if (tid < 8) {
    const int s = tid;
    float fp = sqrtf(sqL[s][0]) + sqrtf(sqL[s][1]) + sqrtf(sqL[s][2]) + sqrtf(sqL[s][3]);
    float rp = 0.f;
    const size_t s8 = (size_t)(sb + s)*8;
    #pragma unroll
    for (int slot = 0; slot < 6; ++slot) {
      const float v = sqP[s8 + slot] + sqP[(size_t)BATCH*8 + s8 + slot]
                    + sqP[2*(size_t)BATCH*8 + s8 + slot] + sqP[3*(size_t)BATCH*8 + s8 + slot];
      const float n = sqrtf(v);
      if (slot < 3) rp += n; else fp += n;
    }
    tot[(size_t)(sb + s)*2 + 0] += fp;
    tot[(size_t)(sb + s)*2 + 1] += rp;
  }
}

// K3: finalize iteration-15 norms, write outputs.
__global__ __launch_bounds__(256) void k3(const float* __restrict__ dlG,
    const float* __restrict__ sqP, const float* __restrict__ cW,
    const float* __restrict__ tot, float* __restrict__ out)
{
  __shared__ float sqL[8][4];
  const int tid = threadIdx.x;
  const int sb = blockIdx.x * 8;
  if (tid < 32) ((float*)sqL)[tid] = 0.f;
  __syncthreads();
  for (int idx = tid; idx < 8*576; idx += 256) {
    const int s = idx / 576, e = idx - s*576;
    const size_t base = (size_t)(sb + s)*768 + e;
    const float d = dlG[base] + dlG[(size_t)BATCH*768 + base]
                  + dlG[2*(size_t)BATCH*768 + base] + dlG[3*(size_t)BATCH*768 + base];
    atomicAdd(&sqL[s][e / NVAR], d * d);
  }
  for (int idx = tid; idx < 8*NVAR; idx += 256) {
    const int s = idx / NVAR, i = idx - s*NVAR;
    out[(size_t)(sb + s)*NVAR + i] = cW[(size_t)(sb + s)*NVAR + i];
  }
  __syncthreads();
  if (tid < 8) {
    const int s = tid;
    float fp = sqrtf(sqL[s][0]) + sqrtf(sqL[s][1]) + sqrtf(sqL[s][2]);
    float rp = 0.f;
    const size_t s8 = (size_t)(sb + s)*8;
    #pragma unroll
    for (int slot = 0; slot < 6; ++slot) {
      const float v = sqP[s8 + slot] + sqP[(size_t)BATCH*8 + s8 + slot]
                    + sqP[2*(size_t)BATCH*8 + s8 + slot] + sqP[3*(size_t)BATCH*8 + s8 + slot];
      const float n = sqrtf(v);
      if (slot < 3) rp += n; else fp += n;
    }
    fp += tot[(size_t)(sb + s)*2 + 0];
    rp += tot[(size_t)(sb + s)*2 + 1];
    out[(size_t)BATCH*NVAR + (sb + s)] = fp * (1.f / MAXITER);
    out[(size_t)BATCH*NVAR + BATCH + (sb + s)] = rp * (1.f / MAXITER);
  }
}

extern "C" void kernel_launch(void* const* d_in, const int* in_sizes, int n_in,
                              void* d_out, int out_size, void* d_ws, size_t ws_size,
                              hipStream_t stream) {
  const float* lamda = (const float*)d_in[0];
  const float* cin   = (const float*)d_in[1];
  const float* c0    = (const float*)d_in[2];
  const float* beq   = (const float*)d_in[3];
  const float* Av    = (const float*)d_in[4];
  const float* Aa    = (const float*)d_in[5];
  const float* Ap    = (const float*)d_in[6];
  const float* Qinv  = (const float*)d_in[7];
  if (ws_size < (size_t)WS_FLOATS * sizeof(float)) return;  // workspace too small: fail visibly

  float* ws   = (float*)d_ws;
  float* lamW = ws + O_LAM;
  float* cW   = ws + O_C;
  float* uW   = ws + O_U;
  float* dlG  = ws + O_DLG;
  float* sqP  = ws + O_SQ;
  float* tot  = ws + O_TOT;
  float* QT   = ws + O_QT;
  float* out  = (float*)d_out;

  const int nz = SZ_DLG + SZ_SQ + SZ_TOT;
  kz<<<(nz + 255)/256, 256, 0, stream>>>(dlG, nz);
  const int nc = SZ_LAM + SZ_C + SZ_QT;
  ki<<<(nc + 255)/256, 256, 0, stream>>>(lamda, c0, Qinv, lamW, cW, QT);

  k2<<<NCHUNK*NTILE, 256, 0, stream>>>(cW, Av, Aa, Ap, uW, dlG, sqP, 1);   // prime: u_0, G_1
  for (int t = 1; t <= MAXITER; ++t) {
    k1<<<BATCH/8, 256, 0, stream>>>(cin, beq, QT, lamW, cW, dlG, sqP, tot);
    k2<<<NCHUNK*NTILE, 256, 0, stream>>>(cW, Av, Aa, Ap, uW, dlG, sqP, 0);
  }
  k3<<<BATCH/8, 256, 0, stream>>>(dlG, sqP, cW, tot, out);
}

// Round 2
// 2494.537 us; speedup vs baseline: 2.9429x; 2.9429x over previous
//
#include <hip/hip_runtime.h>

// MLPProjectionFilter: 15-iter ADMM projection, B=2048, MFMA split-bf16 edition.
// v = A x, res = relu(v-b), u = min(v,b); dl = A^T res; G = sum_mat A^T u.
// A pre-split into bf16 hi/lo (error ~2^-17) and pre-swizzled into MFMA
// A-operand layout (fwd: Ah/Al, transposed: Ath/Atl), rows padded 1200->1280.
// mfma_f32_16x16x32_bf16 layouts (learn_hip m89/m120):
//   A-frag: A[m=lane&15][k=(lane>>4)*8+j], B-frag: B[k=(lane>>4)*8+j][n=lane&15]
//   C/D:    col(n)=lane&15, row(m)=(lane>>4)*4+reg

#define BATCH 2048
#define NVAR 192
#define NROW 1200
#define RPAD 1280
#define NEQ 30
#define NT 222
#define MAXITER 15
#define MTILE 16
#define NTILE 128
#define NCHUNK 2
#define RBC 40            // row-blocks (of 16) per chunk
#define KBC 20            // K-blocks (of 32) per chunk for transpose
#define LPITCH 648        // LDS ushort pitch per sample row (640 rows + pad)

typedef short s16x8 __attribute__((ext_vector_type(8)));
typedef float f32x4 __attribute__((ext_vector_type(4)));
#define MFMA16(a,b,c) __builtin_amdgcn_mfma_f32_16x16x32_bf16(a, b, c, 0, 0, 0)

// ---- workspace layout (float offsets) ----
#define O_LAM 0u
#define SZ_LAM (BATCH*576)                      // 1,179,648
#define O_C   (O_LAM + SZ_LAM)
#define SZ_C  (BATCH*NVAR)                      // 393,216
#define O_U   (O_C + SZ_C)
#define SZ_U  (3*NROW*BATCH)                    // 7,372,800
#define O_DLG (O_U + SZ_U)                      // [2][4][192][2048]
#define SZ_DLG (NCHUNK*4*NVAR*BATCH)            // 3,145,728
#define O_SQ  (O_DLG + SZ_DLG)                  // [2][2048][8]
#define SZ_SQ (NCHUNK*BATCH*8)
#define O_TOT (O_SQ + SZ_SQ)                    // [2048][2]
#define SZ_TOT (BATCH*2)
#define O_QT  (O_TOT + SZ_TOT)
#define SZ_QT (NT*NVAR)
#define O_XH  (O_QT + SZ_QT)                    // ushort[2048*192] in float units
#define SZ_XS (BATCH*NVAR/2)
#define O_XL  (O_XH + SZ_XS)
#define O_AH  (O_XL + SZ_XS)                    // ushort[3*80*6*512]
#define SZ_AS (3*80*6*512/2)                    // 368,640 floats
#define O_AL  (O_AH + SZ_AS)
#define O_ATH (O_AL + SZ_AS)                    // ushort[3*12*40*512]
#define O_ATL (O_ATH + SZ_AS)
#define WS_FLOATS (O_ATL + SZ_AS)               // 14,038,656 floats = 56.2 MB

__device__ inline void bsplit(float v, unsigned short& h, unsigned short& l) {
  union { float f; unsigned u; } a; a.f = v;
  unsigned r = a.u + 0x7FFFu + ((a.u >> 16) & 1u);
  h = (unsigned short)(r >> 16);
  union { unsigned u; float f; } hf; hf.u = (unsigned)h << 16;
  float res = v - hf.f;
  union { float f; unsigned u; } b2; b2.f = res;
  unsigned r2 = b2.u + 0x7FFFu + ((b2.u >> 16) & 1u);
  l = (unsigned short)(r2 >> 16);
}

__global__ __launch_bounds__(256) void kz(float* __restrict__ p, int n) {
  int idx = blockIdx.x * 256 + threadIdx.x;
  if (idx < n) p[idx] = 0.f;
}

// init: copy lam, c, transpose Qinv, split c0 -> xh/xl
__global__ __launch_bounds__(256) void ki(const float* __restrict__ lamda,
    const float* __restrict__ c0, const float* __restrict__ Qinv,
    float* __restrict__ lamW, float* __restrict__ cW, float* __restrict__ QT,
    unsigned short* __restrict__ xh, unsigned short* __restrict__ xl) {
  int idx = blockIdx.x * 256 + threadIdx.x;
  if (idx < BATCH*576) { lamW[idx] = lamda[idx]; return; }
  idx -= BATCH*576;
  if (idx < BATCH*NVAR) { cW[idx] = c0[idx]; return; }
  idx -= BATCH*NVAR;
  if (idx < NT*NVAR) {
    int j = idx / NVAR, i = idx - j*NVAR;
    QT[idx] = Qinv[(size_t)i*NT + j];
    return;
  }
  idx -= NT*NVAR;
  if (idx < BATCH*NVAR) {
    unsigned short h, l;
    bsplit(c0[idx], h, l);
    xh[idx] = h; xl[idx] = l;
  }
}

// build swizzled A operands (fwd + transposed), bf16 hi/lo, zero row-padding
__global__ __launch_bounds__(256) void kA(const float* __restrict__ Av,
    const float* __restrict__ Aa, const float* __restrict__ Ap,
    unsigned short* __restrict__ Ah, unsigned short* __restrict__ Al,
    unsigned short* __restrict__ Ath, unsigned short* __restrict__ Atl) {
  int idx = blockIdx.x * 256 + threadIdx.x;
  const int HALF = 3*80*6*512;       // 737,280
  if (idx >= 2*HALF) return;
  int row, col, oi;
  unsigned short *ph, *pl;
  if (idx < HALF) {
    oi = idx;
    int j = idx & 7; int lane = (idx >> 3) & 63;
    int kb = (idx >> 9) % 6; int rb = (idx >> 9) / 6 % 80; int mat = idx / (80*6*512);
    row = rb*16 + (lane & 15);
    col = kb*32 + (lane >> 4)*8 + j;
    (void)mat;
    const float* A = (idx / (80*6*512) == 0) ? Av : ((idx / (80*6*512) == 1) ? Aa : Ap);
    float v = (row < NROW) ? A[(size_t)row*NVAR + col] : 0.f;
    unsigned short h, l; bsplit(v, h, l);
    Ah[oi] = h; Al[oi] = l;
  } else {
    oi = idx - HALF;
    int j = oi & 7; int lane = (oi >> 3) & 63;
    int kbr = (oi >> 9) % 40; int cb = (oi >> 9) / 40 % 12; int mat = oi / (12*40*512);
    row = kbr*32 + (lane >> 4)*8 + j;
    col = cb*16 + (lane & 15);
    const float* A = (mat == 0) ? Av : ((mat == 1) ? Aa : Ap);
    float v = (row < NROW) ? A[(size_t)row*NVAR + col] : 0.f;
    unsigned short h, l; bsplit(v, h, l);
    Ath[oi] = h; Atl[oi] = l;
  }
}

// K2: MFMA A-streamer. grid = NCHUNK*NTILE = 256, block = 512 (8 waves).
__global__ __launch_bounds__(512) void k2(
    const unsigned short* __restrict__ Ah, const unsigned short* __restrict__ Al,
    const unsigned short* __restrict__ Ath, const unsigned short* __restrict__ Atl,
    const unsigned short* __restrict__ xh, const unsigned short* __restrict__ xl,
    float* __restrict__ uW, float* __restrict__ dlG, float* __restrict__ sqP, int first)
{
  __shared__ unsigned short rhL[16*LPITCH];
  __shared__ unsigned short rlL[16*LPITCH];
  __shared__ unsigned short uhL[16*LPITCH];
  __shared__ unsigned short ulL[16*LPITCH];
  __shared__ float sqAcc[96];                  // [slot 6][n 16]

  const int tid = threadIdx.x;
  const int wave = tid >> 6, lane = tid & 63;
  const int n = lane & 15, q = lane >> 4;
  const int tile = blockIdx.x & (NTILE - 1);
  const int chunk = blockIdx.x >> 7;
  const int tile0 = tile * MTILE;

  if (tid < 96) sqAcc[tid] = 0.f;

  // x B-frags (identical across waves), kept in registers
  s16x8 xfh[6], xfl[6];
  {
    const size_t xo = (size_t)(tile0 + n) * NVAR + q * 8;
    #pragma unroll
    for (int kb = 0; kb < 6; ++kb) {
      xfh[kb] = *(const s16x8*)(xh + xo + kb*32);
      xfl[kb] = *(const s16x8*)(xl + xo + kb*32);
    }
  }
  f32x4 Gacc[2];
  Gacc[0] = (f32x4){0.f,0.f,0.f,0.f};
  Gacc[1] = (f32x4){0.f,0.f,0.f,0.f};
  __syncthreads();

  #pragma unroll 1
  for (int mat = 0; mat < 3; ++mat) {
    const float b = (mat == 0) ? 0.8f : ((mat == 1) ? 1.8f : 3.14159265358979f);
    float rsq = 0.f, ssq = 0.f;

    // ---- forward: 5 row-blocks per wave ----
    #pragma unroll 1
    for (int i = 0; i < 5; ++i) {
      const int rbl = wave*5 + i;               // 0..39 (chunk-local)
      const int rb = chunk*RBC + rbl;           // 0..79 global
      f32x4 acc = (f32x4){0.f,0.f,0.f,0.f};
      const size_t abase = ((size_t)(mat*80 + rb)*6)*512 + (size_t)lane*8;
      #pragma unroll
      for (int kb = 0; kb < 6; ++kb) {
        s16x8 ah = *(const s16x8*)(Ah + abase + (size_t)kb*512);
        s16x8 al = *(const s16x8*)(Al + abase + (size_t)kb*512);
        acc = MFMA16(ah, xfh[kb], acc);
        acc = MFMA16(ah, xfl[kb], acc);
        acc = MFMA16(al, xfh[kb], acc);
      }
      const int rowg = rb*16 + q*4;
      unsigned short rh4[4], rl4[4], uh4[4], ul4[4];
      #pragma unroll
      for (int reg = 0; reg < 4; ++reg) {
        const float v = acc[reg];
        const float rs = fmaxf(v - b, 0.f);
        const float u = fminf(v, b);
        const int r = rowg + reg;
        const size_t ui = ((size_t)mat*NROW + r)*BATCH + tile0 + n;
        if (!first) {
          rsq += rs * rs;
          if (r < NROW) { const float up = uW[ui]; const float sd = u - up; ssq += sd * sd; }
        }
        if (r < NROW) uW[ui] = u;
        bsplit(rs, rh4[reg], rl4[reg]);
        bsplit(u,  uh4[reg], ul4[reg]);
      }
      const int lo = n*LPITCH + rbl*16 + q*4;   // ushort offset, 8B aligned
      uint2 p;
      p.x = (unsigned)rh4[0] | ((unsigned)rh4[1] << 16);
      p.y = (unsigned)rh4[2] | ((unsigned)rh4[3] << 16);
      *(uint2*)(rhL + lo) = p;
      p.x = (unsigned)rl4[0] | ((unsigned)rl4[1] << 16);
      p.y = (unsigned)rl4[2] | ((unsigned)rl4[3] << 16);
      *(uint2*)(rlL + lo) = p;
      p.x = (unsigned)uh4[0] | ((unsigned)uh4[1] << 16);
      p.y = (unsigned)uh4[2] | ((unsigned)uh4[3] << 16);
      *(uint2*)(uhL + lo) = p;
      p.x = (unsigned)ul4[0] | ((unsigned)ul4[1] << 16);
      p.y = (unsigned)ul4[2] | ((unsigned)ul4[3] << 16);
      *(uint2*)(ulL + lo) = p;
    }

    if (!first) {
      rsq += __shfl_xor(rsq, 16); rsq += __shfl_xor(rsq, 32);
      ssq += __shfl_xor(ssq, 16); ssq += __shfl_xor(ssq, 32);
      if (q == 0) {
        atomicAdd(&sqAcc[mat*16 + n], rsq);
        atomicAdd(&sqAcc[(3 + mat)*16 + n], ssq);
      }
    }
    __syncthreads();   // res/u tiles ready

    // ---- transpose: dl = A^T res, G += A^T u ----
    #pragma unroll 1
    for (int ci = 0; ci < 2; ++ci) {
      if (ci == 1 && wave >= 4) break;
      const int cb = (ci == 0) ? wave : wave + 8;
      f32x4 dacc = (f32x4){0.f,0.f,0.f,0.f};
      f32x4 g = Gacc[ci];
      const size_t tb = ((size_t)(mat*12 + cb)*40 + chunk*KBC)*512 + (size_t)lane*8;
      const int lb = n*LPITCH + q*8;
      if (!first) {
        #pragma unroll 2
        for (int kk = 0; kk < KBC; ++kk) {
          s16x8 th = *(const s16x8*)(Ath + tb + (size_t)kk*512);
          s16x8 tl = *(const s16x8*)(Atl + tb + (size_t)kk*512);
          s16x8 rh = *(const s16x8*)(rhL + lb + kk*32);
          s16x8 rl = *(const s16x8*)(rlL + lb + kk*32);
          s16x8 uh = *(const s16x8*)(uhL + lb + kk*32);
          s16x8 ul = *(const s16x8*)(ulL + lb + kk*32);
          dacc = MFMA16(th, rh, dacc);
          dacc = MFMA16(th, rl, dacc);
          dacc = MFMA16(tl, rh, dacc);
          g = MFMA16(th, uh, g);
          g = MFMA16(th, ul, g);
          g = MFMA16(tl, uh, g);
        }
        #pragma unroll
        for (int reg = 0; reg < 4; ++reg)
          dlG[((size_t)(chunk*4 + mat)*NVAR + cb*16 + q*4 + reg)*BATCH + tile0 + n] = dacc[reg];
      } else {
        #pragma unroll 2
        for (int kk = 0; kk < KBC; ++kk) {
          s16x8 th = *(const s16x8*)(Ath + tb + (size_t)kk*512);
          s16x8 tl = *(const s16x8*)(Atl + tb + (size_t)kk*512);
          s16x8 uh = *(const s16x8*)(uhL + lb + kk*32);
          s16x8 ul = *(const s16x8*)(ulL + lb + kk*32);
          g = MFMA16(th, uh, g);
          g = MFMA16(th, ul, g);
          g = MFMA16(tl, uh, g);
        }
      }
      Gacc[ci] = g;
    }
    __syncthreads();   // before next mat overwrites LDS
  }

  // flush G (slot 3)
  #pragma unroll 1
  for (int ci = 0; ci < 2; ++ci) {
    if (ci == 1 && wave >= 4) break;
    const int cb = (ci == 0) ? wave : wave + 8;
    #pragma unroll
    for (int reg = 0; reg < 4; ++reg)
      dlG[((size_t)(chunk*4 + 3)*NVAR + cb*16 + q*4 + reg)*BATCH + tile0 + n] = Gacc[ci][reg];
  }

  __syncthreads();
  if (!first && tid < 96) {
    const int s = tid & 15, slot = tid >> 4;
    sqP[((size_t)chunk*BATCH + tile0 + s)*8 + slot] = sqAcc[slot*16 + s];
  }
}

// K1: per-sample solve. grid = BATCH/8 = 256, block = 256.
__global__ __launch_bounds__(256) void k1(const float* __restrict__ cin,
    const float* __restrict__ beq, const float* __restrict__ QT,
    float* __restrict__ lamW, float* __restrict__ cW,
    const float* __restrict__ dlG, const float* __restrict__ sqP,
    float* __restrict__ tot, unsigned short* __restrict__ xh,
    unsigned short* __restrict__ xl)
{
  __shared__ float dlL[8][776];     // [s][slot*192+j], pitch-padded
  __shared__ float lamL[8][576];
  __shared__ float rhsL[8][NT];
  __shared__ float sqL[8][4];
  const int tid = threadIdx.x;
  const int sb = blockIdx.x * 8;
  if (tid < 32) ((float*)sqL)[tid] = 0.f;
  // sum dl/G chunk partials; s-fastest mapping for coalescing
  for (int idx = tid; idx < 8*768; idx += 256) {
    const int s = idx & 7, e = idx >> 3;
    const size_t base = (size_t)e*BATCH + sb + s;
    dlL[s][e] = dlG[base] + dlG[(size_t)4*NVAR*BATCH + base];
  }
  __syncthreads();
  // lam update + ||dl|| partials
  for (int idx = tid; idx < 8*576; idx += 256) {
    const int s = idx / 576, e = idx - s*576;
    const size_t g = (size_t)(sb + s)*576 + e;
    const float d = dlL[s][e];
    const float ln = lamW[g] - d;
    lamW[g] = ln;
    lamL[s][e] = ln;
    atomicAdd(&sqL[s][e / NVAR], d * d);
  }
  __syncthreads();
  // rhs = [lam_v+lam_a+lam_p + c_in + G ; b_eq]
  for (int idx = tid; idx < 8*NT; idx += 256) {
    const int s = idx / NT, j = idx - s*NT;
    float v;
    if (j < NVAR)
      v = lamL[s][j] + lamL[s][NVAR + j] + lamL[s][2*NVAR + j]
        + cin[(size_t)(sb + s)*NVAR + j] + dlL[s][576 + j];
    else
      v = beq[(size_t)(sb + s)*NEQ + (j - NVAR)];
    rhsL[s][j] = v;
  }
  __syncthreads();
  // primal[i] = sum_j QT[j][i] * rhs[j]
  if (tid < NVAR) {
    float acc[8];
    #pragma unroll
    for (int s = 0; s < 8; ++s) acc[s] = 0.f;
    #pragma unroll 2
    for (int j = 0; j < NT; ++j) {
      const float qv = QT[(size_t)j*NVAR + tid];
      #pragma unroll
      for (int s = 0; s < 8; ++s) acc[s] = fmaf(qv, rhsL[s][j], acc[s]);
    }
    #pragma unroll
    for (int s = 0; s < 8; ++s) {
      const size_t g = (size_t)(sb + s)*NVAR + tid;
      const float co = cW[g];
      const float d = acc[s] - co;
      atomicAdd(&sqL[s][3], d * d);
      cW[g] = acc[s];
      unsigned short h, l;
      bsplit(acc[s], h, l);
      xh[g] = h; xl[g] = l;
    }
  }
  __syncthreads();
  if (tid < 8) {
    const int s = tid;
    float fp = sqrtf(sqL[s][0]) + sqrtf(sqL[s][1]) + sqrtf(sqL[s][2]) + sqrtf(sqL[s][3]);
    float rp = 0.f;
    const size_t s8 = (size_t)(sb + s)*8;
    #pragma unroll
    for (int slot = 0; slot < 6; ++slot) {
      const float v = sqP[s8 + slot] + sqP[(size_t)BATCH*8 + s8 + slot];
      const float nn = sqrtf(v);
      if (slot < 3) rp += nn; else fp += nn;
    }
    tot[(size_t)(sb + s)*2 + 0] += fp;
    tot[(size_t)(sb + s)*2 + 1] += rp;
  }
}

// K3: finalize iteration-15 norms, write outputs.
__global__ __launch_bounds__(256) void k3(const float* __restrict__ dlG,
    const float* __restrict__ sqP, const float* __restrict__ cW,
    const float* __restrict__ tot, float* __restrict__ out)
{
  __shared__ float sqL[8][4];
  const int tid = threadIdx.x;
  const int sb = blockIdx.x * 8;
  if (tid < 32) ((float*)sqL)[tid] = 0.f;
  __syncthreads();
  for (int idx = tid; idx < 8*576; idx += 256) {
    const int s = idx & 7, e = idx >> 3;
    const size_t base = (size_t)e*BATCH + sb + s;   // slots 0..2 are the first 576 rows
    const float d = dlG[base] + dlG[(size_t)4*NVAR*BATCH + base];
    atomicAdd(&sqL[s][e / NVAR], d * d);
  }
  for (int idx = tid; idx < 8*NVAR; idx += 256) {
    const int s = idx / NVAR, i = idx - s*NVAR;
    out[(size_t)(sb + s)*NVAR + i] = cW[(size_t)(sb + s)*NVAR + i];
  }
  __syncthreads();
  if (tid < 8) {
    const int s = tid;
    float fp = sqrtf(sqL[s][0]) + sqrtf(sqL[s][1]) + sqrtf(sqL[s][2]);
    float rp = 0.f;
    const size_t s8 = (size_t)(sb + s)*8;
    #pragma unroll
    for (int slot = 0; slot < 6; ++slot) {
      const float v = sqP[s8 + slot] + sqP[(size_t)BATCH*8 + s8 + slot];
      const float nn = sqrtf(v);
      if (slot < 3) rp += nn; else fp += nn;
    }
    fp += tot[(size_t)(sb + s)*2 + 0];
    rp += tot[(size_t)(sb + s)*2 + 1];
    out[(size_t)BATCH*NVAR + (sb + s)] = fp * (1.f / MAXITER);
    out[(size_t)BATCH*NVAR + BATCH + (sb + s)] = rp * (1.f / MAXITER);
  }
}

extern "C" void kernel_launch(void* const* d_in, const int* in_sizes, int n_in,
                              void* d_out, int out_size, void* d_ws, size_t ws_size,
                              hipStream_t stream) {
  const float* lamda = (const float*)d_in[0];
  const float* cin   = (const float*)d_in[1];
  const float* c0    = (const float*)d_in[2];
  const float* beq   = (const float*)d_in[3];
  const float* Av    = (const float*)d_in[4];
  const float* Aa    = (const float*)d_in[5];
  const float* Ap    = (const float*)d_in[6];
  const float* Qinv  = (const float*)d_in[7];
  if (ws_size < (size_t)WS_FLOATS * sizeof(float)) return;

  float* ws   = (float*)d_ws;
  float* lamW = ws + O_LAM;
  float* cW   = ws + O_C;
  float* uW   = ws + O_U;
  float* dlG  = ws + O_DLG;
  float* sqP  = ws + O_SQ;
  float* tot  = ws + O_TOT;
  float* QT   = ws + O_QT;
  unsigned short* xh  = (unsigned short*)(ws + O_XH);
  unsigned short* xl  = (unsigned short*)(ws + O_XL);
  unsigned short* Ah  = (unsigned short*)(ws + O_AH);
  unsigned short* Al  = (unsigned short*)(ws + O_AL);
  unsigned short* Ath = (unsigned short*)(ws + O_ATH);
  unsigned short* Atl = (unsigned short*)(ws + O_ATL);
  float* out  = (float*)d_out;

  const int nz = SZ_DLG + SZ_SQ + SZ_TOT;
  kz<<<(nz + 255)/256, 256, 0, stream>>>(dlG, nz);
  const int nc = SZ_LAM + SZ_C + SZ_QT + BATCH*NVAR;
  ki<<<(nc + 255)/256, 256, 0, stream>>>(lamda, c0, Qinv, lamW, cW, QT, xh, xl);
  const int na = 2*3*80*6*512;
  kA<<<(na + 255)/256, 256, 0, stream>>>(Av, Aa, Ap, Ah, Al, Ath, Atl);

  k2<<<NCHUNK*NTILE, 512, 0, stream>>>(Ah, Al, Ath, Atl, xh, xl, uW, dlG, sqP, 1);
  for (int t = 1; t <= MAXITER; ++t) {
    k1<<<BATCH/8, 256, 0, stream>>>(cin, beq, QT, lamW, cW, dlG, sqP, tot, xh, xl);
    k2<<<NCHUNK*NTILE, 512, 0, stream>>>(Ah, Al, Ath, Atl, xh, xl, uW, dlG, sqP, 0);
  }
  k3<<<BATCH/8, 256, 0, stream>>>(dlG, sqP, cW, tot, out);
}